// Round 1
// baseline (149.967 us; speedup 1.0000x reference)
//
#include <hip/hip_runtime.h>
#include <hip/hip_bf16.h>

#define NB 8
#define ND 768
#define NCH 3
#define NMIX 5
#define NH 10
#define NS 10

#define PI2F 6.283185307179586f
#define HALF_PI2SQ 19.739208802178716f   // 0.5 * (2*pi)^2
#define ZITTERF 1e-4f

// cos(2*pi*t) via hardware v_cos (input in revolutions), with fract range-reduction
__device__ __forceinline__ float cos2pi(float t) {
    return __builtin_amdgcn_cosf(__builtin_amdgcn_fractf(t));
}

// ---------------------------------------------------------------------------
// Kernel A: feature[b,i,c,m] = sum_j K[b,m,i,j,c]*yc[b,j,c]; writes tif[b,i,c,0..5]
// One wave (64 lanes) per (b,i,c) row; lanes stride over j; shfl reduction.
// ---------------------------------------------------------------------------
__global__ void __launch_bounds__(256) feature_kernel(
        const float* __restrict__ xc, const float* __restrict__ yc,
        const float* __restrict__ mu, const float* __restrict__ istd,
        float* __restrict__ tif) {
    const int wid  = (blockIdx.x << 2) + (threadIdx.x >> 6);
    const int lane = threadIdx.x & 63;
    const int b   = wid / (ND * NCH);
    const int rem = wid % (ND * NCH);
    const int i = rem / NCH;
    const int c = rem % NCH;

    float cmu[NMIX], cexp[NMIX];
#pragma unroll
    for (int m = 0; m < NMIX; ++m) {
        const float is = istd[m];
        cmu[m]  = mu[m];
        cexp[m] = -HALF_PI2SQ * is * is;
    }

    const float xi = xc[(b * ND + i) * NCH + c];
    float acc[NMIX] = {0.f, 0.f, 0.f, 0.f, 0.f};

    for (int j = lane; j < ND; j += 64) {
        const float xj = xc[(b * ND + j) * NCH + c];
        const float yj = yc[(b * ND + j) * NCH + c];
        const float dx  = xi - xj;
        const float dx2 = dx * dx;
#pragma unroll
        for (int m = 0; m < NMIX; ++m) {
            const float e  = __expf(cexp[m] * dx2);
            const float co = cos2pi(cmu[m] * dx);
            acc[m] += e * co * yj;
        }
    }

#pragma unroll
    for (int m = 0; m < NMIX; ++m)
        for (int off = 32; off; off >>= 1)
            acc[m] += __shfl_down(acc[m], off);

    if (lane == 0) {
        const float yi = yc[(b * ND + i) * NCH + c];
        float* tp = tif + ((b * ND + i) * NCH + c) * (NMIX + 1);
#pragma unroll
        for (int m = 0; m < NMIX; ++m) tp[m] = acc[m] + ZITTERF * yi;
        tp[NMIX] = yi;
    }
}

// ---------------------------------------------------------------------------
// Kernel B: per-batch MLP + Gumbel-softmax -> w[b, c*5+m] (15 floats per batch)
// One block per batch.
// ---------------------------------------------------------------------------
__global__ void __launch_bounds__(256) mlp_gumbel_kernel(
        const float* __restrict__ tif,
        const float* __restrict__ W1, const float* __restrict__ b1,
        const float* __restrict__ W2, const float* __restrict__ b2,
        const float* __restrict__ W3, const float* __restrict__ b3,
        const float* __restrict__ W4, const float* __restrict__ b4,
        const float* __restrict__ W5, const float* __restrict__ b5,
        const float* __restrict__ unif,
        float* __restrict__ wout) {
    const int b   = blockIdx.x;
    const int tid = threadIdx.x;

    __shared__ float sW1[NH * 6], sb1[NH];
    __shared__ float red[4][NCH * NH];
    __shared__ float hvec[NCH * NH], h2[NH], h3[NH], h4[NH], ll[NCH * NMIX], wacc[NCH * NMIX];

    if (tid < NH * 6) sW1[tid] = W1[tid];
    if (tid < NH)     sb1[tid] = b1[tid];
    if (tid < NCH * NMIX) wacc[tid] = 0.f;
    __syncthreads();

    float part[NCH * NH];
#pragma unroll
    for (int t = 0; t < NCH * NH; ++t) part[t] = 0.f;

    for (int ii = tid; ii < ND; ii += 256) {
        for (int c = 0; c < NCH; ++c) {
            const float* tp = tif + ((b * ND + ii) * NCH + c) * (NMIX + 1);
            float f[6];
#pragma unroll
            for (int m = 0; m < 6; ++m) f[m] = tp[m];
#pragma unroll
            for (int k = 0; k < NH; ++k) {
                float a = sb1[k];
#pragma unroll
                for (int m = 0; m < 6; ++m) a += f[m] * sW1[k * 6 + m];
                part[c * NH + k] += fmaxf(a, 0.f);
            }
        }
    }

#pragma unroll
    for (int t = 0; t < NCH * NH; ++t)
        for (int off = 32; off; off >>= 1)
            part[t] += __shfl_down(part[t], off);

    const int lane = tid & 63, wv = tid >> 6;
    if (lane == 0)
        for (int t = 0; t < NCH * NH; ++t) red[wv][t] = part[t];
    __syncthreads();

    if (tid < NCH * NH)
        hvec[tid] = (red[0][tid] + red[1][tid] + red[2][tid] + red[3][tid]) * (1.f / (float)ND);
    __syncthreads();

    if (tid < NH) {
        float a = b2[tid];
        for (int j = 0; j < NCH * NH; ++j) a += W2[tid * (NCH * NH) + j] * hvec[j];
        h2[tid] = fmaxf(a, 0.f);
    }
    __syncthreads();
    if (tid < NH) {
        float a = b3[tid];
        for (int j = 0; j < NH; ++j) a += W3[tid * NH + j] * h2[j];
        h3[tid] = fmaxf(a, 0.f);
    }
    __syncthreads();
    if (tid < NH) {
        float a = b4[tid];
        for (int j = 0; j < NH; ++j) a += W4[tid * NH + j] * h3[j];
        h4[tid] = fmaxf(a, 0.f);
    }
    __syncthreads();
    if (tid < NCH * NMIX) {
        float a = b5[tid];
        for (int j = 0; j < NH; ++j) a += W5[tid * NH + j] * h4[j];
        ll[tid] = a;
    }
    __syncthreads();

    // Gumbel-softmax: threads 0..29 handle (s, c) pairs; mean over ns=10 samples
    if (tid < NS * NCH) {
        const int s = tid / NCH, c = tid % NCH;
        float z[NMIX], zmax = -1e30f;
#pragma unroll
        for (int m = 0; m < NMIX; ++m) {
            const float u = unif[((b * NS + s) * NCH + c) * NMIX + m];
            const float g = -__logf(-__logf(u + 1e-20f));
            z[m] = (g + ll[c * NMIX + m]) * 10.0f;   // / TEMP(=0.1)
            zmax = fmaxf(zmax, z[m]);
        }
        float e[NMIX], se = 0.f;
#pragma unroll
        for (int m = 0; m < NMIX; ++m) { e[m] = __expf(z[m] - zmax); se += e[m]; }
        const float inv = 0.1f / se;  // 1/sum * 1/ns
#pragma unroll
        for (int m = 0; m < NMIX; ++m)
            atomicAdd(&wacc[c * NMIX + m], e[m] * inv);
    }
    __syncthreads();
    if (tid < NCH * NMIX) wout[b * (NCH * NMIX) + tid] = wacc[tid];
}

// ---------------------------------------------------------------------------
// Kernel C: weighted[b,i,j,c] = sum_m w[b,c,m]*K[b,m,i,j,c] (+diag). One thread
// per (b,i,j), all 3 channels; block covers fixed (b,i), 256 consecutive j.
// ---------------------------------------------------------------------------
__global__ void __launch_bounds__(256) weighted_kernel(
        const float* __restrict__ xc, const float* __restrict__ wmix,
        const float* __restrict__ mu, const float* __restrict__ istd,
        const float* __restrict__ likerr,
        float* __restrict__ out) {
    const int b   = blockIdx.x / ((ND * ND) / 256);            // 2304 blocks per b
    const int rem = blockIdx.x % ((ND * ND) / 256);
    const int i   = rem / (ND / 256);                           // 3 blocks per i
    const int j   = (rem % (ND / 256)) * 256 + threadIdx.x;
    const int tid = threadIdx.x;

    __shared__ float sw[NCH * NMIX], smu[NMIX], sce[NMIX], sdiag[NCH], sxi[NCH];
    if (tid < NCH * NMIX) sw[tid] = wmix[b * (NCH * NMIX) + tid];
    if (tid < NMIX) {
        smu[tid] = mu[tid];
        const float is = istd[tid];
        sce[tid] = -HALF_PI2SQ * is * is;
    }
    if (tid < NCH) {
        const float lk = fminf(fmaxf(likerr[tid], 0.1f), 1.0f);
        sdiag[tid] = ZITTERF + lk * lk;
        sxi[tid]   = xc[(b * ND + i) * NCH + tid];
    }
    __syncthreads();

    float xj[NCH];
#pragma unroll
    for (int c = 0; c < NCH; ++c) xj[c] = xc[(b * ND + j) * NCH + c];

    float res[NCH];
#pragma unroll
    for (int c = 0; c < NCH; ++c) {
        const float dx  = sxi[c] - xj[c];
        const float dx2 = dx * dx;
        float a = 0.f;
#pragma unroll
        for (int m = 0; m < NMIX; ++m)
            a += sw[c * NMIX + m] * __expf(sce[m] * dx2) * cos2pi(smu[m] * dx);
        if (i == j) a += sdiag[c];
        res[c] = a;
    }

    float* op = out + (size_t)((b * ND + i) * ND + j) * NCH;
    op[0] = res[0];
    op[1] = res[1];
    op[2] = res[2];
}

extern "C" void kernel_launch(void* const* d_in, const int* in_sizes, int n_in,
                              void* d_out, int out_size, void* d_ws, size_t ws_size,
                              hipStream_t stream) {
    const float* xc     = (const float*)d_in[0];
    const float* yc     = (const float*)d_in[1];
    const float* mu     = (const float*)d_in[2];
    const float* istd   = (const float*)d_in[3];
    const float* likerr = (const float*)d_in[4];
    const float* unif   = (const float*)d_in[5];
    const float* W1 = (const float*)d_in[6];  const float* b1 = (const float*)d_in[7];
    const float* W2 = (const float*)d_in[8];  const float* b2 = (const float*)d_in[9];
    const float* W3 = (const float*)d_in[10]; const float* b3 = (const float*)d_in[11];
    const float* W4 = (const float*)d_in[12]; const float* b4 = (const float*)d_in[13];
    const float* W5 = (const float*)d_in[14]; const float* b5 = (const float*)d_in[15];

    float* out  = (float*)d_out;
    float* tif  = (float*)d_ws;                       // NB*ND*NCH*6 = 110592 floats
    float* wmix = tif + NB * ND * NCH * (NMIX + 1);   // NB*15 = 120 floats

    // A: one wave per (b,i,c) -> 8*768*3 = 18432 waves = 4608 blocks
    feature_kernel<<<(NB * ND * NCH) / 4, 256, 0, stream>>>(xc, yc, mu, istd, tif);

    // B: one block per batch
    mlp_gumbel_kernel<<<NB, 256, 0, stream>>>(tif, W1, b1, W2, b2, W3, b3, W4, b4,
                                              W5, b5, unif, wmix);

    // C: one thread per (b,i,j) -> 8*768*768/256 = 18432 blocks
    weighted_kernel<<<(NB * ND * ND) / 256, 256, 0, stream>>>(xc, wmix, mu, istd,
                                                              likerr, out);
}